// Round 1
// baseline (671.013 us; speedup 1.0000x reference)
//
#include <hip/hip_runtime.h>
#include <math.h>

#define N_NODES 50000
#define N_EDGES 800000
#define IN_CH   256
#define OUT_CH  64
#define HEADS   4
#define NEG_SLOPE 0.2f
#define TOT_E   (N_EDGES + N_NODES)   // edges + self loops = 850000

// ---------------------------------------------------------------------------
// Kernel 1: per-node transform.
//   xw[n,:]   = x[n,:] @ W          (256 -> 256)
//   xres[n,:] = x[n,:] @ W_res      (256 -> 64)
//   asrc[n,h] = sum_c xw[n,h*64+c] * att_src[h,c]
//   adst[n,h] = sum_c xw[n,h*64+c] * att_dst[h,c]
// 8 nodes per block of 256 threads; x rows staged in LDS (broadcast reads),
// W/W_res read coalesced from L2 (256KB, fully L2-resident across blocks).
// One wave == one head (OUT_CH==64==wave size) -> shuffle reduction for logits.
// ---------------------------------------------------------------------------
__global__ __launch_bounds__(256) void node_transform(
    const float* __restrict__ x, const float* __restrict__ W,
    const float* __restrict__ Wres, const float* __restrict__ attS,
    const float* __restrict__ attD,
    float* __restrict__ xw, float* __restrict__ xres,
    float* __restrict__ asrc, float* __restrict__ adst)
{
    __shared__ float xs[8][IN_CH];
    const int t  = threadIdx.x;
    const int n0 = blockIdx.x * 8;

    // stage 8 x-rows (2048 floats = 512 float4, 2 per thread)
    const float4* xsrc = reinterpret_cast<const float4*>(x + (size_t)n0 * IN_CH);
    float4* xs4 = reinterpret_cast<float4*>(&xs[0][0]);
    xs4[t]       = xsrc[t];
    xs4[t + 256] = xsrc[t + 256];
    __syncthreads();

    // xw: thread t computes column t for all 8 nodes
    float acc[8] = {0.f,0.f,0.f,0.f,0.f,0.f,0.f,0.f};
    for (int c4 = 0; c4 < IN_CH / 4; ++c4) {
        const float w0 = W[(c4*4 + 0) * 256 + t];
        const float w1 = W[(c4*4 + 1) * 256 + t];
        const float w2 = W[(c4*4 + 2) * 256 + t];
        const float w3 = W[(c4*4 + 3) * 256 + t];
        #pragma unroll
        for (int i = 0; i < 8; ++i) {
            const float4 xv = reinterpret_cast<const float4*>(&xs[i][0])[c4];
            acc[i] = fmaf(xv.x, w0, acc[i]);
            acc[i] = fmaf(xv.y, w1, acc[i]);
            acc[i] = fmaf(xv.z, w2, acc[i]);
            acc[i] = fmaf(xv.w, w3, acc[i]);
        }
    }
    #pragma unroll
    for (int i = 0; i < 8; ++i)
        xw[(size_t)(n0 + i) * IN_CH + t] = acc[i];

    // attention logits: wave h handles head h (t = h*64 + cc)
    const int h  = t >> 6;
    const int cc = t & 63;
    const float aS = attS[h * 64 + cc];
    const float aD = attD[h * 64 + cc];
    #pragma unroll
    for (int i = 0; i < 8; ++i) {
        float vs = acc[i] * aS;
        float vd = acc[i] * aD;
        #pragma unroll
        for (int off = 32; off >= 1; off >>= 1) {
            vs += __shfl_xor(vs, off);
            vd += __shfl_xor(vd, off);
        }
        if (cc == 0) {
            asrc[(n0 + i) * HEADS + h] = vs;
            adst[(n0 + i) * HEADS + h] = vd;
        }
    }

    // x_res: wave g computes nodes g and g+4, lane cc = output column
    float r0 = 0.f, r1 = 0.f;
    for (int c4 = 0; c4 < IN_CH / 4; ++c4) {
        const float w0 = Wres[(c4*4 + 0) * 64 + cc];
        const float w1 = Wres[(c4*4 + 1) * 64 + cc];
        const float w2 = Wres[(c4*4 + 2) * 64 + cc];
        const float w3 = Wres[(c4*4 + 3) * 64 + cc];
        const float4 xa = reinterpret_cast<const float4*>(&xs[h][0])[c4];
        const float4 xb = reinterpret_cast<const float4*>(&xs[h + 4][0])[c4];
        r0 = fmaf(xa.x, w0, r0); r0 = fmaf(xa.y, w1, r0);
        r0 = fmaf(xa.z, w2, r0); r0 = fmaf(xa.w, w3, r0);
        r1 = fmaf(xb.x, w0, r1); r1 = fmaf(xb.y, w1, r1);
        r1 = fmaf(xb.z, w2, r1); r1 = fmaf(xb.w, w3, r1);
    }
    xres[(size_t)(n0 + h) * OUT_CH + cc]     = r0;
    xres[(size_t)(n0 + h + 4) * OUT_CH + cc] = r1;
}

// ---------------------------------------------------------------------------
// Kernel 2: softmax denominator. softmax is shift-invariant; magnitudes here
// (|alpha| ~ few) make the reference's segment_max pass unnecessary in fp32.
// ---------------------------------------------------------------------------
__device__ __forceinline__ float lrelu(float v) {
    return v > 0.f ? v : NEG_SLOPE * v;
}

__global__ __launch_bounds__(256) void edge_denom(
    const int* __restrict__ ei, const float* __restrict__ asrc,
    const float* __restrict__ adst, float* __restrict__ denom)
{
    const int e = blockIdx.x * 256 + threadIdx.x;
    if (e >= TOT_E) return;
    int s, d;
    if (e < N_EDGES) { s = ei[e]; d = ei[N_EDGES + e]; }
    else             { s = e - N_EDGES; d = s; }
    const float4 as = reinterpret_cast<const float4*>(asrc)[s];
    const float4 ad = reinterpret_cast<const float4*>(adst)[d];
    const float e0 = __expf(lrelu(as.x + ad.x));
    const float e1 = __expf(lrelu(as.y + ad.y));
    const float e2 = __expf(lrelu(as.z + ad.z));
    const float e3 = __expf(lrelu(as.w + ad.w));
    atomicAdd(&denom[d * HEADS + 0], e0);
    atomicAdd(&denom[d * HEADS + 1], e1);
    atomicAdd(&denom[d * HEADS + 2], e2);
    atomicAdd(&denom[d * HEADS + 3], e3);
}

// ---------------------------------------------------------------------------
// Kernel 3: weighted aggregation, head-mean folded in.
// One wave per edge; lane == output channel. Per edge:
//   agg[dst,c] += 0.25 * sum_h (e_h / denom[dst,h]) * xw[src, h*64+c]
// ---------------------------------------------------------------------------
__global__ __launch_bounds__(256) void edge_aggregate(
    const int* __restrict__ ei, const float* __restrict__ asrc,
    const float* __restrict__ adst, const float* __restrict__ denom,
    const float* __restrict__ xw, float* __restrict__ agg)
{
    const int lane = threadIdx.x & 63;
    const int e = blockIdx.x * 4 + (threadIdx.x >> 6);
    if (e >= TOT_E) return;
    int s, d;
    if (e < N_EDGES) { s = ei[e]; d = ei[N_EDGES + e]; }
    else             { s = e - N_EDGES; d = s; }
    const float4 as = reinterpret_cast<const float4*>(asrc)[s];
    const float4 ad = reinterpret_cast<const float4*>(adst)[d];
    const float4 dn = reinterpret_cast<const float4*>(denom)[d];
    const float w0 = 0.25f * __fdividef(__expf(lrelu(as.x + ad.x)), dn.x);
    const float w1 = 0.25f * __fdividef(__expf(lrelu(as.y + ad.y)), dn.y);
    const float w2 = 0.25f * __fdividef(__expf(lrelu(as.z + ad.z)), dn.z);
    const float w3 = 0.25f * __fdividef(__expf(lrelu(as.w + ad.w)), dn.w);
    const float* xr = xw + (size_t)s * IN_CH;
    float v = w0 * xr[lane] + w1 * xr[64 + lane]
            + w2 * xr[128 + lane] + w3 * xr[192 + lane];
    atomicAdd(&agg[(size_t)d * OUT_CH + lane], v);
}

// ---------------------------------------------------------------------------
// Kernel 4: out = relu(agg + bias + x_res)
// ---------------------------------------------------------------------------
__global__ __launch_bounds__(256) void finalize(
    const float* __restrict__ agg, const float* __restrict__ xres,
    const float* __restrict__ bias, float* __restrict__ out)
{
    const int i = blockIdx.x * 256 + threadIdx.x;
    if (i >= N_NODES * OUT_CH) return;
    const float v = agg[i] + xres[i] + bias[i & 63];
    out[i] = v > 0.f ? v : 0.f;
}

extern "C" void kernel_launch(void* const* d_in, const int* in_sizes, int n_in,
                              void* d_out, int out_size, void* d_ws, size_t ws_size,
                              hipStream_t stream) {
    const float* x    = (const float*)d_in[0];
    const int*   ei   = (const int*)d_in[1];
    const float* W    = (const float*)d_in[2];
    const float* attS = (const float*)d_in[3];
    const float* attD = (const float*)d_in[4];
    const float* bias = (const float*)d_in[5];
    const float* Wres = (const float*)d_in[6];
    float* out = (float*)d_out;

    float* ws    = (float*)d_ws;
    float* xw    = ws;                                  // N*256
    float* xres  = xw   + (size_t)N_NODES * IN_CH;      // N*64
    float* asrc  = xres + (size_t)N_NODES * OUT_CH;     // N*4
    float* adst  = asrc + (size_t)N_NODES * HEADS;      // N*4
    float* denom = adst + (size_t)N_NODES * HEADS;      // N*4
    float* agg   = denom + (size_t)N_NODES * HEADS;     // N*64 (contiguous w/ denom)

    // zero denom + agg in one shot (they are adjacent)
    hipMemsetAsync(denom, 0,
                   (size_t)N_NODES * (HEADS + OUT_CH) * sizeof(float), stream);

    node_transform<<<N_NODES / 8, 256, 0, stream>>>(
        x, W, Wres, attS, attD, xw, xres, asrc, adst);
    edge_denom<<<(TOT_E + 255) / 256, 256, 0, stream>>>(ei, asrc, adst, denom);
    edge_aggregate<<<(TOT_E + 3) / 4, 256, 0, stream>>>(
        ei, asrc, adst, denom, xw, agg);
    finalize<<<(N_NODES * OUT_CH + 255) / 256, 256, 0, stream>>>(
        agg, xres, bias, out);
}

// Round 2
// 496.920 us; speedup vs baseline: 1.3503x; 1.3503x over previous
//
#include <hip/hip_runtime.h>
#include <math.h>

#define N_NODES 50000
#define N_EDGES 800000
#define IN_CH   256
#define OUT_CH  64
#define HEADS   4
#define NEG_SLOPE 0.2f
#define TM      16   // nodes per block in node_transform

__device__ __forceinline__ float lrelu(float v) {
    return v > 0.f ? v : NEG_SLOPE * v;
}

// ---------------------------------------------------------------------------
// Kernel 1: per-node transform, register-tiled.
// Block = 256 threads = 4 waves; wave ng handles nodes {4ng..4ng+3}; lane cg
// handles xw cols {4cg..4cg+3} and xres col cg. 16 accumulators/thread for xw
// + 4 for xres, all fed from the same LDS x fragments (4 ds_read_b128 per
// k4-chunk vs 80 FMAs -> FMA-issue-bound, ~52us floor).
// ---------------------------------------------------------------------------
__global__ __launch_bounds__(256) void node_transform(
    const float* __restrict__ x, const float* __restrict__ W,
    const float* __restrict__ Wres, const float* __restrict__ attS,
    const float* __restrict__ attD,
    float* __restrict__ xw, float* __restrict__ xres,
    float* __restrict__ asrc, float* __restrict__ adst)
{
    __shared__ float xs[TM][IN_CH];
    const int t  = threadIdx.x;
    const int n0 = blockIdx.x * TM;

    // stage TM x-rows: 1024 float4, 4 per thread
    {
        const float4* xsrc = reinterpret_cast<const float4*>(x + (size_t)n0 * IN_CH);
        float4* xs4 = reinterpret_cast<float4*>(&xs[0][0]);
        #pragma unroll
        for (int i = 0; i < 4; ++i) xs4[t + 256 * i] = xsrc[t + 256 * i];
    }
    __syncthreads();

    const int cg = t & 63;        // lane
    const int ng = t >> 6;        // wave -> node group
    const int c0 = cg * 4;        // first xw column

    float4 acc[4];
    float  r[4];
    #pragma unroll
    for (int i = 0; i < 4; ++i) { acc[i] = make_float4(0.f,0.f,0.f,0.f); r[i] = 0.f; }

    for (int k4 = 0; k4 < IN_CH / 4; ++k4) {
        float4 xv[4];
        #pragma unroll
        for (int i = 0; i < 4; ++i)
            xv[i] = *reinterpret_cast<const float4*>(&xs[ng * 4 + i][k4 * 4]);
        #pragma unroll
        for (int j = 0; j < 4; ++j) {
            const int k = k4 * 4 + j;
            const float4 w  = *reinterpret_cast<const float4*>(W + (size_t)k * 256 + c0);
            const float  wr = Wres[(size_t)k * 64 + cg];
            #pragma unroll
            for (int i = 0; i < 4; ++i) {
                const float xk = (j == 0) ? xv[i].x : (j == 1) ? xv[i].y
                               : (j == 2) ? xv[i].z : xv[i].w;
                acc[i].x = fmaf(xk, w.x, acc[i].x);
                acc[i].y = fmaf(xk, w.y, acc[i].y);
                acc[i].z = fmaf(xk, w.z, acc[i].z);
                acc[i].w = fmaf(xk, w.w, acc[i].w);
                r[i]     = fmaf(xk, wr,  r[i]);
            }
        }
    }

    // store xw (coalesced float4) and xres
    #pragma unroll
    for (int i = 0; i < 4; ++i) {
        *reinterpret_cast<float4*>(xw + (size_t)(n0 + ng * 4 + i) * IN_CH + c0) = acc[i];
        xres[(size_t)(n0 + ng * 4 + i) * OUT_CH + cg] = r[i];
    }

    // attention logits: head h = cg>>4; lanes 16h..16h+15 hold that head's cols
    const int h = cg >> 4;
    const float4 aS = *reinterpret_cast<const float4*>(attS + h * 64 + (cg & 15) * 4);
    const float4 aD = *reinterpret_cast<const float4*>(attD + h * 64 + (cg & 15) * 4);
    #pragma unroll
    for (int i = 0; i < 4; ++i) {
        float vs = acc[i].x * aS.x + acc[i].y * aS.y + acc[i].z * aS.z + acc[i].w * aS.w;
        float vd = acc[i].x * aD.x + acc[i].y * aD.y + acc[i].z * aD.z + acc[i].w * aD.w;
        #pragma unroll
        for (int off = 8; off >= 1; off >>= 1) {
            vs += __shfl_xor(vs, off);
            vd += __shfl_xor(vd, off);
        }
        if ((cg & 15) == 0) {
            asrc[(n0 + ng * 4 + i) * HEADS + h] = vs;
            adst[(n0 + ng * 4 + i) * HEADS + h] = vd;
        }
    }
}

// ---------------------------------------------------------------------------
// CSR build: histogram -> exclusive scan -> scatter
// ---------------------------------------------------------------------------
__global__ __launch_bounds__(256) void histogram(
    const int* __restrict__ ei, int* __restrict__ cnt)
{
    const int e = blockIdx.x * 256 + threadIdx.x;
    if (e >= N_EDGES) return;
    atomicAdd(&cnt[ei[N_EDGES + e]], 1);
}

__global__ __launch_bounds__(1024) void scan_kernel(
    const int* __restrict__ cnt, int* __restrict__ rowstart)
{
    __shared__ int wsums[16];
    __shared__ int carry_s;
    const int t = threadIdx.x;
    const int lane = t & 63, w = t >> 6;
    if (t == 0) carry_s = 0;
    __syncthreads();
    for (int base = 0; base < N_NODES; base += 1024) {
        const int i = base + t;
        const int v = (i < N_NODES) ? cnt[i] : 0;
        int sc = v;
        #pragma unroll
        for (int off = 1; off < 64; off <<= 1) {
            int n = __shfl_up(sc, off);
            if (lane >= off) sc += n;
        }
        if (lane == 63) wsums[w] = sc;
        __syncthreads();
        if (t < 16) {
            int s = wsums[t];
            #pragma unroll
            for (int off = 1; off < 16; off <<= 1) {
                int n = __shfl_up(s, off);
                if (t >= off) s += n;
            }
            wsums[t] = s;
        }
        __syncthreads();
        const int wofs = (w == 0) ? 0 : wsums[w - 1];
        if (i < N_NODES) rowstart[i] = carry_s + wofs + sc - v;
        __syncthreads();
        if (t == 0) carry_s += wsums[15];
        __syncthreads();
    }
}

__global__ __launch_bounds__(256) void scatter(
    const int* __restrict__ ei, const int* __restrict__ rowstart,
    int* __restrict__ fill, int* __restrict__ esrc)
{
    const int e = blockIdx.x * 256 + threadIdx.x;
    if (e >= N_EDGES) return;
    const int d = ei[N_EDGES + e];
    const int pos = atomicAdd(&fill[d], 1);
    esrc[rowstart[d] + pos] = ei[e];
}

// ---------------------------------------------------------------------------
// Kernel 5: fused softmax-denominator + weighted aggregation + epilogue.
// One wave per dst node; lane = output channel.
// pass1: denom lane-parallel over incident edges + butterfly reduce.
// pass2: sequential edges, acc_c += sum_h w_h * xw[src, h*64+c].
// Self-loop folded in analytically; head-mean (0.25) folded into inv-denoms.
// ---------------------------------------------------------------------------
__global__ __launch_bounds__(256) void aggregate(
    const int* __restrict__ esrc, const int* __restrict__ rowstart,
    const int* __restrict__ cnt, const float* __restrict__ asrc,
    const float* __restrict__ adst, const float* __restrict__ xw,
    const float* __restrict__ xres, const float* __restrict__ bias,
    float* __restrict__ out)
{
    const int lane = threadIdx.x & 63;
    const int d = blockIdx.x * 4 + (threadIdx.x >> 6);
    if (d >= N_NODES) return;
    const int row = rowstart[d];
    const int deg = cnt[d];
    const float4 ad = *reinterpret_cast<const float4*>(adst + (size_t)d * 4);

    // pass 1: softmax denominator, lane-parallel
    float dn0 = 0.f, dn1 = 0.f, dn2 = 0.f, dn3 = 0.f;
    for (int e = lane; e < deg; e += 64) {
        const int s = esrc[row + e];
        const float4 as = *reinterpret_cast<const float4*>(asrc + (size_t)s * 4);
        dn0 += __expf(lrelu(as.x + ad.x));
        dn1 += __expf(lrelu(as.y + ad.y));
        dn2 += __expf(lrelu(as.z + ad.z));
        dn3 += __expf(lrelu(as.w + ad.w));
    }
    #pragma unroll
    for (int off = 32; off >= 1; off >>= 1) {
        dn0 += __shfl_xor(dn0, off);
        dn1 += __shfl_xor(dn1, off);
        dn2 += __shfl_xor(dn2, off);
        dn3 += __shfl_xor(dn3, off);
    }
    // self-loop contribution
    const float4 asd = *reinterpret_cast<const float4*>(asrc + (size_t)d * 4);
    const float s0 = __expf(lrelu(asd.x + ad.x));
    const float s1 = __expf(lrelu(asd.y + ad.y));
    const float s2 = __expf(lrelu(asd.z + ad.z));
    const float s3 = __expf(lrelu(asd.w + ad.w));
    const float i0 = 0.25f / (dn0 + s0);
    const float i1 = 0.25f / (dn1 + s1);
    const float i2 = 0.25f / (dn2 + s2);
    const float i3 = 0.25f / (dn3 + s3);

    // pass 2: aggregate (init with self-loop)
    const float* xd = xw + (size_t)d * IN_CH;
    float acc = s0 * i0 * xd[lane]        + s1 * i1 * xd[64 + lane]
              + s2 * i2 * xd[128 + lane]  + s3 * i3 * xd[192 + lane];
    for (int e = 0; e < deg; ++e) {
        const int s = esrc[row + e];
        const float4 as = *reinterpret_cast<const float4*>(asrc + (size_t)s * 4);
        const float w0 = __expf(lrelu(as.x + ad.x)) * i0;
        const float w1 = __expf(lrelu(as.y + ad.y)) * i1;
        const float w2 = __expf(lrelu(as.z + ad.z)) * i2;
        const float w3 = __expf(lrelu(as.w + ad.w)) * i3;
        const float* xr = xw + (size_t)s * IN_CH;
        acc += w0 * xr[lane] + w1 * xr[64 + lane]
             + w2 * xr[128 + lane] + w3 * xr[192 + lane];
    }
    const float v = acc + bias[lane] + xres[(size_t)d * OUT_CH + lane];
    out[(size_t)d * OUT_CH + lane] = fmaxf(v, 0.f);
}

extern "C" void kernel_launch(void* const* d_in, const int* in_sizes, int n_in,
                              void* d_out, int out_size, void* d_ws, size_t ws_size,
                              hipStream_t stream) {
    const float* x    = (const float*)d_in[0];
    const int*   ei   = (const int*)d_in[1];
    const float* W    = (const float*)d_in[2];
    const float* attS = (const float*)d_in[3];
    const float* attD = (const float*)d_in[4];
    const float* bias = (const float*)d_in[5];
    const float* Wres = (const float*)d_in[6];
    float* out = (float*)d_out;

    char* ws = (char*)d_ws;
    float* xw       = (float*)ws;                      ws += (size_t)N_NODES * IN_CH  * 4;
    float* xres     = (float*)ws;                      ws += (size_t)N_NODES * OUT_CH * 4;
    float* asrc     = (float*)ws;                      ws += (size_t)N_NODES * HEADS  * 4;
    float* adst     = (float*)ws;                      ws += (size_t)N_NODES * HEADS  * 4;
    int*   cnt      = (int*)ws;                        ws += (size_t)N_NODES * 4;
    int*   fill     = (int*)ws;                        ws += (size_t)N_NODES * 4;
    int*   rowstart = (int*)ws;                        ws += (size_t)N_NODES * 4;
    int*   esrc     = (int*)ws;                        ws += (size_t)N_EDGES * 4;

    // zero cnt + fill (adjacent)
    hipMemsetAsync(cnt, 0, (size_t)N_NODES * 2 * sizeof(int), stream);

    histogram<<<(N_EDGES + 255) / 256, 256, 0, stream>>>(ei, cnt);
    scan_kernel<<<1, 1024, 0, stream>>>(cnt, rowstart);
    scatter<<<(N_EDGES + 255) / 256, 256, 0, stream>>>(ei, rowstart, fill, esrc);
    node_transform<<<N_NODES / TM, 256, 0, stream>>>(
        x, W, Wres, attS, attD, xw, xres, asrc, adst);
    aggregate<<<N_NODES / 4, 256, 0, stream>>>(
        esrc, rowstart, cnt, asrc, adst, xw, xres, bias, out);
}

// Round 3
// 342.042 us; speedup vs baseline: 1.9618x; 1.4528x over previous
//
#include <hip/hip_runtime.h>
#include <math.h>

#define N_NODES 50000
#define N_EDGES 800000
#define IN_CH   256
#define OUT_CH  64
#define HEADS   4
#define NEG_SLOPE 0.2f
#define NCOLS   320           // W (256) || W_res (64)
#define NTILES  20            // NCOLS / 16
#define NKK     8             // IN_CH / 32

typedef __attribute__((ext_vector_type(8))) short short8;
typedef __attribute__((ext_vector_type(4))) float f32x4;

__device__ __forceinline__ float lrelu(float v) {
    return v > 0.f ? v : NEG_SLOPE * v;
}
__device__ __forceinline__ unsigned bf16_rne(float f) {
    unsigned u = __float_as_uint(f);
    return (u + 0x7FFFu + ((u >> 16) & 1u)) >> 16;
}
__device__ __forceinline__ unsigned pack2(float lo, float hi) {
    return bf16_rne(lo) | (bf16_rne(hi) << 16);
}
__device__ __forceinline__ float bflo(unsigned u) { return __uint_as_float(u << 16); }
__device__ __forceinline__ float bfhi(unsigned u) { return __uint_as_float(u & 0xFFFF0000u); }
__device__ __forceinline__ short8 as_short8(uint4 u) {
    union { uint4 u4; short8 s8; } cv; cv.u4 = u; return cv.s8;
}

// ---------------------------------------------------------------------------
// pack_B: [W | W_res] (fp32) -> bf16 MFMA B-fragment order.
// Bp[(kk*NTILES + t)*64 + lane] = uint4 of 8 bf16:
//   B[k = kk*32 + (lane>>4)*8 + j][col = t*16 + (lane&15)], j=0..7
// ---------------------------------------------------------------------------
__global__ __launch_bounds__(256) void pack_B(
    const float* __restrict__ W, const float* __restrict__ Wres,
    uint4* __restrict__ Bp)
{
    const int idx = blockIdx.x * 256 + threadIdx.x;      // 0..10239
    if (idx >= NKK * NTILES * 64) return;
    const int kk   = idx / (NTILES * 64);
    const int rem  = idx - kk * (NTILES * 64);
    const int t    = rem >> 6;
    const int lane = rem & 63;
    const int colL = lane & 15, quad = lane >> 4;
    const int col  = t * 16 + colL;
    const int k0   = kk * 32 + quad * 8;
    float v[8];
    #pragma unroll
    for (int j = 0; j < 8; ++j) {
        const int k = k0 + j;
        v[j] = (col < IN_CH) ? W[(size_t)k * IN_CH + col]
                             : Wres[(size_t)k * OUT_CH + (col - IN_CH)];
    }
    uint4 u;
    u.x = pack2(v[0], v[1]); u.y = pack2(v[2], v[3]);
    u.z = pack2(v[4], v[5]); u.w = pack2(v[6], v[7]);
    Bp[(kk * NTILES + t) * 64 + lane] = u;
}

// ---------------------------------------------------------------------------
// MFMA node transform: xw(bf16 packed) + xres(fp32) + attention logits.
// Block = 256 thr = 4 waves, 64 nodes/block. Wave wv: rows wv*16..wv*16+15,
// all 320 cols = 20 MFMA 16x16x32 tiles, K-loop of 8.
// A staged in LDS in fragment order (x fp32 -> bf16). B read from global Bp
// (160 KB, L2-resident, shared by all blocks).
// Epilogue: C/D layout col=lane&15, row=(lane>>4)*4+reg.
//   - a_src/a_dst via per-head dot + 16-lane shuffle reduce
//   - xw stored packed bf16x2: xwp[row][hp*64 + tsub*16 + colL] = (h_even,h_odd)
//   - cols 256..319 -> xres fp32
// ---------------------------------------------------------------------------
__global__ __launch_bounds__(256) void gemm_node(
    const float* __restrict__ x, const uint4* __restrict__ Bp,
    const float* __restrict__ attS, const float* __restrict__ attD,
    unsigned* __restrict__ xwp, float* __restrict__ xres,
    float* __restrict__ asrc, float* __restrict__ adst)
{
    __shared__ uint4 Alds[4 * NKK * 64];   // 32 KB
    const int tid = threadIdx.x;
    const int n0  = blockIdx.x * 64;

    // stage A: 2048 fragment entries, 8 per thread
    #pragma unroll
    for (int i = 0; i < 8; ++i) {
        const int e    = i * 256 + tid;
        const int g    = e >> 9;
        const int kk   = (e >> 6) & 7;
        const int lane = e & 63;
        const int colL = lane & 15, quad = lane >> 4;
        const int row  = n0 + g * 16 + colL;
        const int k0   = kk * 32 + quad * 8;
        uint4 u = make_uint4(0u, 0u, 0u, 0u);
        if (row < N_NODES) {
            const float4 a = *reinterpret_cast<const float4*>(x + (size_t)row * IN_CH + k0);
            const float4 b = *reinterpret_cast<const float4*>(x + (size_t)row * IN_CH + k0 + 4);
            u.x = pack2(a.x, a.y); u.y = pack2(a.z, a.w);
            u.z = pack2(b.x, b.y); u.w = pack2(b.z, b.w);
        }
        Alds[(g * NKK + kk) * 64 + lane] = u;
    }
    __syncthreads();

    const int lane = tid & 63;
    const int wv   = tid >> 6;
    const int colL = lane & 15, quad = lane >> 4;

    f32x4 acc[NTILES];
    #pragma unroll
    for (int t = 0; t < NTILES; ++t) acc[t] = (f32x4){0.f, 0.f, 0.f, 0.f};

    for (int kk = 0; kk < NKK; ++kk) {
        const short8 a = as_short8(Alds[(wv * NKK + kk) * 64 + lane]);
        // two halves of 10 tiles to bound VGPR pressure
        #pragma unroll
        for (int half = 0; half < 2; ++half) {
            uint4 bu[10];
            #pragma unroll
            for (int t = 0; t < 10; ++t)
                bu[t] = Bp[(kk * NTILES + half * 10 + t) * 64 + lane];
            #pragma unroll
            for (int t = 0; t < 10; ++t)
                acc[half * 10 + t] = __builtin_amdgcn_mfma_f32_16x16x32_bf16(
                    a, as_short8(bu[t]), acc[half * 10 + t], 0, 0, 0);
        }
    }

    // rows this lane holds: n0 + wv*16 + quad*4 + r
    const int rbase = n0 + wv * 16 + quad * 4;

    // attention logits
    #pragma unroll
    for (int h = 0; h < HEADS; ++h) {
        float vs[4] = {0.f, 0.f, 0.f, 0.f}, vd[4] = {0.f, 0.f, 0.f, 0.f};
        #pragma unroll
        for (int tt = 0; tt < 4; ++tt) {
            const int t2 = h * 4 + tt;
            const float aSv = attS[h * 64 + tt * 16 + colL];
            const float aDv = attD[h * 64 + tt * 16 + colL];
            #pragma unroll
            for (int r = 0; r < 4; ++r) {
                vs[r] = fmaf(acc[t2][r], aSv, vs[r]);
                vd[r] = fmaf(acc[t2][r], aDv, vd[r]);
            }
        }
        #pragma unroll
        for (int off = 8; off >= 1; off >>= 1) {
            #pragma unroll
            for (int r = 0; r < 4; ++r) {
                vs[r] += __shfl_xor(vs[r], off);
                vd[r] += __shfl_xor(vd[r], off);
            }
        }
        if (colL == 0) {
            #pragma unroll
            for (int r = 0; r < 4; ++r) {
                const int row = rbase + r;
                if (row < N_NODES) {
                    asrc[row * HEADS + h] = vs[r];
                    adst[row * HEADS + h] = vd[r];
                }
            }
        }
    }

    // packed xw: head pair hp holds (h=2hp, h=2hp+1) -> tiles hp*8+tt, hp*8+4+tt
    #pragma unroll
    for (int hp = 0; hp < 2; ++hp) {
        #pragma unroll
        for (int tt = 0; tt < 4; ++tt) {
            #pragma unroll
            for (int r = 0; r < 4; ++r) {
                const int row = rbase + r;
                if (row < N_NODES) {
                    xwp[(size_t)row * 128 + hp * 64 + tt * 16 + colL] =
                        pack2(acc[hp * 8 + tt][r], acc[hp * 8 + 4 + tt][r]);
                }
            }
        }
    }

    // xres = cols 256..319
    #pragma unroll
    for (int tt = 0; tt < 4; ++tt) {
        #pragma unroll
        for (int r = 0; r < 4; ++r) {
            const int row = rbase + r;
            if (row < N_NODES)
                xres[(size_t)row * OUT_CH + tt * 16 + colL] = acc[16 + tt][r];
        }
    }
}

// ---------------------------------------------------------------------------
// CSR build: histogram -> 2-level scan -> scatter
// ---------------------------------------------------------------------------
__global__ __launch_bounds__(256) void histogram(
    const int* __restrict__ ei, int* __restrict__ cnt)
{
    const int e = blockIdx.x * 256 + threadIdx.x;
    if (e >= N_EDGES) return;
    atomicAdd(&cnt[ei[N_EDGES + e]], 1);
}

__global__ __launch_bounds__(256) void scan_local(
    const int* __restrict__ cnt, int* __restrict__ lscan, int* __restrict__ bsum)
{
    __shared__ int ws[4];
    const int t = threadIdx.x, lane = t & 63, w = t >> 6;
    const int i = blockIdx.x * 256 + t;
    const int v = (i < N_NODES) ? cnt[i] : 0;
    int sc = v;
    #pragma unroll
    for (int off = 1; off < 64; off <<= 1) {
        const int n = __shfl_up(sc, off);
        if (lane >= off) sc += n;
    }
    if (lane == 63) ws[w] = sc;
    __syncthreads();
    int prefix = 0;
    for (int j = 0; j < w; ++j) prefix += ws[j];
    if (i < N_NODES) lscan[i] = prefix + sc - v;
    if (t == 255) bsum[blockIdx.x] = prefix + sc;
}

__global__ __launch_bounds__(256) void scan_bsum(
    const int* __restrict__ bsum, int* __restrict__ bsumx, int nblk)
{
    __shared__ int ws[4];
    const int t = threadIdx.x, lane = t & 63, w = t >> 6;
    const int v = (t < nblk) ? bsum[t] : 0;
    int sc = v;
    #pragma unroll
    for (int off = 1; off < 64; off <<= 1) {
        const int n = __shfl_up(sc, off);
        if (lane >= off) sc += n;
    }
    if (lane == 63) ws[w] = sc;
    __syncthreads();
    int prefix = 0;
    for (int j = 0; j < w; ++j) prefix += ws[j];
    if (t < nblk) bsumx[t] = prefix + sc - v;
}

__global__ __launch_bounds__(256) void scatter(
    const int* __restrict__ ei, const int* __restrict__ lscan,
    const int* __restrict__ bsumx, int* __restrict__ fill, int* __restrict__ esrc)
{
    const int e = blockIdx.x * 256 + threadIdx.x;
    if (e >= N_EDGES) return;
    const int d = ei[N_EDGES + e];
    const int pos = atomicAdd(&fill[d], 1);
    esrc[lscan[d] + bsumx[d >> 8] + pos] = ei[e];
}

// ---------------------------------------------------------------------------
// aggregate: one wave per dst node, lane = channel.
// pass1 denom lane-parallel; pass2 sequential, xw gathered as packed bf16x2
// (512 B/edge). Self-loop analytic; head-mean folded into inv-denoms.
// ---------------------------------------------------------------------------
__global__ __launch_bounds__(256) void aggregate(
    const int* __restrict__ esrc, const int* __restrict__ lscan,
    const int* __restrict__ bsumx, const int* __restrict__ cnt,
    const float* __restrict__ asrc, const float* __restrict__ adst,
    const unsigned* __restrict__ xwp, const float* __restrict__ xres,
    const float* __restrict__ bias, float* __restrict__ out)
{
    const int lane = threadIdx.x & 63;
    const int d = blockIdx.x * 4 + (threadIdx.x >> 6);
    if (d >= N_NODES) return;
    const int row = lscan[d] + bsumx[d >> 8];
    const int deg = cnt[d];
    const float4 ad = *reinterpret_cast<const float4*>(adst + (size_t)d * 4);

    // pass 1: softmax denominator
    float dn0 = 0.f, dn1 = 0.f, dn2 = 0.f, dn3 = 0.f;
    for (int e = lane; e < deg; e += 64) {
        const int s = esrc[row + e];
        const float4 as = *reinterpret_cast<const float4*>(asrc + (size_t)s * 4);
        dn0 += __expf(lrelu(as.x + ad.x));
        dn1 += __expf(lrelu(as.y + ad.y));
        dn2 += __expf(lrelu(as.z + ad.z));
        dn3 += __expf(lrelu(as.w + ad.w));
    }
    #pragma unroll
    for (int off = 32; off >= 1; off >>= 1) {
        dn0 += __shfl_xor(dn0, off);
        dn1 += __shfl_xor(dn1, off);
        dn2 += __shfl_xor(dn2, off);
        dn3 += __shfl_xor(dn3, off);
    }
    const float4 asd = *reinterpret_cast<const float4*>(asrc + (size_t)d * 4);
    const float s0 = __expf(lrelu(asd.x + ad.x));
    const float s1 = __expf(lrelu(asd.y + ad.y));
    const float s2 = __expf(lrelu(asd.z + ad.z));
    const float s3 = __expf(lrelu(asd.w + ad.w));
    const float i0 = 0.25f / (dn0 + s0);
    const float i1 = 0.25f / (dn1 + s1);
    const float i2 = 0.25f / (dn2 + s2);
    const float i3 = 0.25f / (dn3 + s3);

    // pass 2: aggregate (self-loop first)
    unsigned u0 = xwp[(size_t)d * 128 + lane];
    unsigned u1 = xwp[(size_t)d * 128 + 64 + lane];
    float acc = s0 * i0 * bflo(u0) + s1 * i1 * bfhi(u0)
              + s2 * i2 * bflo(u1) + s3 * i3 * bfhi(u1);
    for (int e = 0; e < deg; ++e) {
        const int s = esrc[row + e];
        const float4 as = *reinterpret_cast<const float4*>(asrc + (size_t)s * 4);
        const float w0 = __expf(lrelu(as.x + ad.x)) * i0;
        const float w1 = __expf(lrelu(as.y + ad.y)) * i1;
        const float w2 = __expf(lrelu(as.z + ad.z)) * i2;
        const float w3 = __expf(lrelu(as.w + ad.w)) * i3;
        const unsigned v0 = xwp[(size_t)s * 128 + lane];
        const unsigned v1 = xwp[(size_t)s * 128 + 64 + lane];
        acc += w0 * bflo(v0) + w1 * bfhi(v0) + w2 * bflo(v1) + w3 * bfhi(v1);
    }
    const float v = acc + bias[lane] + xres[(size_t)d * OUT_CH + lane];
    out[(size_t)d * OUT_CH + lane] = fmaxf(v, 0.f);
}

extern "C" void kernel_launch(void* const* d_in, const int* in_sizes, int n_in,
                              void* d_out, int out_size, void* d_ws, size_t ws_size,
                              hipStream_t stream) {
    const float* x    = (const float*)d_in[0];
    const int*   ei   = (const int*)d_in[1];
    const float* W    = (const float*)d_in[2];
    const float* attS = (const float*)d_in[3];
    const float* attD = (const float*)d_in[4];
    const float* bias = (const float*)d_in[5];
    const float* Wres = (const float*)d_in[6];
    float* out = (float*)d_out;

    char* p = (char*)d_ws;
    uint4*    Bp    = (uint4*)p;      p += (size_t)NKK * NTILES * 64 * 16;   // 160 KB
    unsigned* xwp   = (unsigned*)p;   p += (size_t)N_NODES * 128 * 4;        // 25.6 MB
    float*    xres  = (float*)p;      p += (size_t)N_NODES * OUT_CH * 4;     // 12.8 MB
    float*    asrc  = (float*)p;      p += (size_t)N_NODES * HEADS * 4;
    float*    adst  = (float*)p;      p += (size_t)N_NODES * HEADS * 4;
    int*      cnt   = (int*)p;        p += (size_t)N_NODES * 4;
    int*      fill  = (int*)p;        p += (size_t)N_NODES * 4;
    int*      lscan = (int*)p;        p += (size_t)N_NODES * 4;
    int*      bsum  = (int*)p;        p += 256 * 4;
    int*      bsumx = (int*)p;        p += 256 * 4;
    int*      esrc  = (int*)p;        p += (size_t)N_EDGES * 4;

    const int nblk_scan = (N_NODES + 255) / 256;   // 196

    hipMemsetAsync(cnt, 0, (size_t)N_NODES * 2 * sizeof(int), stream);

    pack_B<<<(NKK * NTILES * 64 + 255) / 256, 256, 0, stream>>>(W, Wres, Bp);
    histogram<<<(N_EDGES + 255) / 256, 256, 0, stream>>>(ei, cnt);
    scan_local<<<nblk_scan, 256, 0, stream>>>(cnt, lscan, bsum);
    scan_bsum<<<1, 256, 0, stream>>>(bsum, bsumx, nblk_scan);
    scatter<<<(N_EDGES + 255) / 256, 256, 0, stream>>>(ei, lscan, bsumx, fill, esrc);
    gemm_node<<<(N_NODES + 63) / 64, 256, 0, stream>>>(
        x, Bp, attS, attD, xwp, xres, asrc, adst);
    aggregate<<<(N_NODES + 3) / 4, 256, 0, stream>>>(
        esrc, lscan, bsumx, cnt, asrc, adst, xwp, xres, bias, out);
}

// Round 4
// 298.589 us; speedup vs baseline: 2.2473x; 1.1455x over previous
//
#include <hip/hip_runtime.h>
#include <math.h>

#define N_NODES 50000
#define N_EDGES 800000
#define IN_CH   256
#define OUT_CH  64
#define HEADS   4
#define NEG_SLOPE 0.2f
#define NCOLS   320           // W (256) || W_res (64)
#define NTILES  20            // NCOLS / 16
#define NKK     8             // IN_CH / 32

typedef __attribute__((ext_vector_type(8))) short short8;
typedef __attribute__((ext_vector_type(4))) float f32x4;

__device__ __forceinline__ float lrelu(float v) {
    return v > 0.f ? v : NEG_SLOPE * v;
}
__device__ __forceinline__ unsigned bf16_rne(float f) {
    unsigned u = __float_as_uint(f);
    return (u + 0x7FFFu + ((u >> 16) & 1u)) >> 16;
}
__device__ __forceinline__ unsigned pack2(float lo, float hi) {
    return bf16_rne(lo) | (bf16_rne(hi) << 16);
}
__device__ __forceinline__ float bflo(unsigned u) { return __uint_as_float(u << 16); }
__device__ __forceinline__ float bfhi(unsigned u) { return __uint_as_float(u & 0xFFFF0000u); }
__device__ __forceinline__ short8 as_short8(uint4 u) {
    union { uint4 u4; short8 s8; } cv; cv.u4 = u; return cv.s8;
}

// ---------------------------------------------------------------------------
// pack_B: [W | W_res] (fp32) -> bf16 MFMA B-fragment order.
// Bp[(kk*NTILES + t)*64 + lane] = uint4 of 8 bf16:
//   B[k = kk*32 + (lane>>4)*8 + j][col = t*16 + (lane&15)], j=0..7
// ---------------------------------------------------------------------------
__global__ __launch_bounds__(256) void pack_B(
    const float* __restrict__ W, const float* __restrict__ Wres,
    uint4* __restrict__ Bp)
{
    const int idx = blockIdx.x * 256 + threadIdx.x;      // 0..10239
    if (idx >= NKK * NTILES * 64) return;
    const int kk   = idx / (NTILES * 64);
    const int rem  = idx - kk * (NTILES * 64);
    const int t    = rem >> 6;
    const int lane = rem & 63;
    const int colL = lane & 15, quad = lane >> 4;
    const int col  = t * 16 + colL;
    const int k0   = kk * 32 + quad * 8;
    float v[8];
    #pragma unroll
    for (int j = 0; j < 8; ++j) {
        const int k = k0 + j;
        v[j] = (col < IN_CH) ? W[(size_t)k * IN_CH + col]
                             : Wres[(size_t)k * OUT_CH + (col - IN_CH)];
    }
    uint4 u;
    u.x = pack2(v[0], v[1]); u.y = pack2(v[2], v[3]);
    u.z = pack2(v[4], v[5]); u.w = pack2(v[6], v[7]);
    Bp[(kk * NTILES + t) * 64 + lane] = u;
}

// ---------------------------------------------------------------------------
// MFMA node transform. Block = 256 thr = 4 waves, 64 nodes/block.
// Wave wv owns column-tiles {wv, 4+wv, 8+wv, 12+wv, 16+wv} (j=0..3 -> head j
// columns wv*16+colL; j=4 -> xres) over ALL 4 row-groups -> each B tile read
// once per block (4x less L2 B-traffic than per-wave-rows mapping).
// Logits need cross-wave sums (each wave holds 16 of 64 head-cols): per-wave
// 16-lane butterfly partials -> LDS -> 256-thread final sum. Keeps fp32 acc
// precision for the logits (don't round through bf16 before the exp).
// C/D layout: col=lane&15, row=(lane>>4)*4+reg.
// ---------------------------------------------------------------------------
__global__ __launch_bounds__(256) void gemm_node(
    const float* __restrict__ x, const uint4* __restrict__ Bp,
    const float* __restrict__ attS, const float* __restrict__ attD,
    unsigned* __restrict__ xwp, float* __restrict__ xres,
    float* __restrict__ asrc, float* __restrict__ adst)
{
    __shared__ uint4 Alds[4 * NKK * 64];   // 32 KB
    __shared__ float partS[4][4][64];      // [wave][head][row-in-block], 4 KB
    __shared__ float partD[4][4][64];      // 4 KB
    const int tid = threadIdx.x;
    const int n0  = blockIdx.x * 64;

    // stage A: 2048 fragment entries, 8 per thread (fp32 -> bf16)
    #pragma unroll
    for (int i = 0; i < 8; ++i) {
        const int e    = i * 256 + tid;
        const int g    = e >> 9;
        const int kk   = (e >> 6) & 7;
        const int lane = e & 63;
        const int cL   = lane & 15, qd = lane >> 4;
        const int row  = n0 + g * 16 + cL;
        const int k0   = kk * 32 + qd * 8;
        uint4 u = make_uint4(0u, 0u, 0u, 0u);
        if (row < N_NODES) {
            const float4 a = *reinterpret_cast<const float4*>(x + (size_t)row * IN_CH + k0);
            const float4 b = *reinterpret_cast<const float4*>(x + (size_t)row * IN_CH + k0 + 4);
            u.x = pack2(a.x, a.y); u.y = pack2(a.z, a.w);
            u.z = pack2(b.x, b.y); u.w = pack2(b.z, b.w);
        }
        Alds[(g * NKK + kk) * 64 + lane] = u;
    }
    __syncthreads();

    const int lane = tid & 63;
    const int wv   = tid >> 6;
    const int colL = lane & 15, quad = lane >> 4;

    f32x4 acc[4][5];   // [row-group][j]
    #pragma unroll
    for (int rg = 0; rg < 4; ++rg)
        #pragma unroll
        for (int j = 0; j < 5; ++j) acc[rg][j] = (f32x4){0.f, 0.f, 0.f, 0.f};

    for (int kk = 0; kk < NKK; ++kk) {
        uint4 bu[5];
        #pragma unroll
        for (int j = 0; j < 5; ++j)
            bu[j] = Bp[(kk * NTILES + j * 4 + wv) * 64 + lane];
        #pragma unroll
        for (int rg = 0; rg < 4; ++rg) {
            const short8 a = as_short8(Alds[(rg * NKK + kk) * 64 + lane]);
            #pragma unroll
            for (int j = 0; j < 5; ++j)
                acc[rg][j] = __builtin_amdgcn_mfma_f32_16x16x32_bf16(
                    a, as_short8(bu[j]), acc[rg][j], 0, 0, 0);
        }
    }

    // ---- logits: per-wave partial dots (cols wv*16+colL), butterfly over 16
    #pragma unroll
    for (int h = 0; h < HEADS; ++h) {
        const float aSv = attS[h * 64 + wv * 16 + colL];
        const float aDv = attD[h * 64 + wv * 16 + colL];
        #pragma unroll
        for (int rg = 0; rg < 4; ++rg) {
            #pragma unroll
            for (int r = 0; r < 4; ++r) {
                float vs = acc[rg][h][r] * aSv;
                float vd = acc[rg][h][r] * aDv;
                #pragma unroll
                for (int off = 8; off >= 1; off >>= 1) {
                    vs += __shfl_xor(vs, off);
                    vd += __shfl_xor(vd, off);
                }
                if (colL == 0) {
                    partS[wv][h][rg * 16 + quad * 4 + r] = vs;
                    partD[wv][h][rg * 16 + quad * 4 + r] = vd;
                }
            }
        }
    }
    __syncthreads();
    {
        const int rowIB = tid & 63, h = tid >> 6;
        const int row = n0 + rowIB;
        if (row < N_NODES) {
            const float vs = partS[0][h][rowIB] + partS[1][h][rowIB]
                           + partS[2][h][rowIB] + partS[3][h][rowIB];
            const float vd = partD[0][h][rowIB] + partD[1][h][rowIB]
                           + partD[2][h][rowIB] + partD[3][h][rowIB];
            asrc[row * HEADS + h] = vs;
            adst[row * HEADS + h] = vd;
        }
    }

    // ---- xw packed bf16x2: (h0,h1) at [0..63], (h2,h3) at [64..127]
    #pragma unroll
    for (int hp = 0; hp < 2; ++hp) {
        #pragma unroll
        for (int rg = 0; rg < 4; ++rg) {
            #pragma unroll
            for (int r = 0; r < 4; ++r) {
                const int row = n0 + rg * 16 + quad * 4 + r;
                if (row < N_NODES)
                    xwp[(size_t)row * 128 + hp * 64 + wv * 16 + colL] =
                        pack2(acc[rg][hp * 2][r], acc[rg][hp * 2 + 1][r]);
            }
        }
    }
    // ---- xres (fp32)
    #pragma unroll
    for (int rg = 0; rg < 4; ++rg) {
        #pragma unroll
        for (int r = 0; r < 4; ++r) {
            const int row = n0 + rg * 16 + quad * 4 + r;
            if (row < N_NODES)
                xres[(size_t)row * OUT_CH + wv * 16 + colL] = acc[rg][4][r];
        }
    }
}

// ---------------------------------------------------------------------------
// CSR build: histogram -> 2-level scan -> scatter
// ---------------------------------------------------------------------------
__global__ __launch_bounds__(256) void histogram(
    const int* __restrict__ ei, int* __restrict__ cnt)
{
    const int e = blockIdx.x * 256 + threadIdx.x;
    if (e >= N_EDGES) return;
    atomicAdd(&cnt[ei[N_EDGES + e]], 1);
}

__global__ __launch_bounds__(256) void scan_local(
    const int* __restrict__ cnt, int* __restrict__ lscan, int* __restrict__ bsum)
{
    __shared__ int ws[4];
    const int t = threadIdx.x, lane = t & 63, w = t >> 6;
    const int i = blockIdx.x * 256 + t;
    const int v = (i < N_NODES) ? cnt[i] : 0;
    int sc = v;
    #pragma unroll
    for (int off = 1; off < 64; off <<= 1) {
        const int n = __shfl_up(sc, off);
        if (lane >= off) sc += n;
    }
    if (lane == 63) ws[w] = sc;
    __syncthreads();
    int prefix = 0;
    for (int j = 0; j < w; ++j) prefix += ws[j];
    if (i < N_NODES) lscan[i] = prefix + sc - v;
    if (t == 255) bsum[blockIdx.x] = prefix + sc;
}

__global__ __launch_bounds__(256) void scan_bsum(
    const int* __restrict__ bsum, int* __restrict__ bsumx, int nblk)
{
    __shared__ int ws[4];
    const int t = threadIdx.x, lane = t & 63, w = t >> 6;
    const int v = (t < nblk) ? bsum[t] : 0;
    int sc = v;
    #pragma unroll
    for (int off = 1; off < 64; off <<= 1) {
        const int n = __shfl_up(sc, off);
        if (lane >= off) sc += n;
    }
    if (lane == 63) ws[w] = sc;
    __syncthreads();
    int prefix = 0;
    for (int j = 0; j < w; ++j) prefix += ws[j];
    if (t < nblk) bsumx[t] = prefix + sc - v;
}

__global__ __launch_bounds__(256) void scatter(
    const int* __restrict__ ei, const int* __restrict__ lscan,
    const int* __restrict__ bsumx, int* __restrict__ fill, int* __restrict__ esrc)
{
    const int e = blockIdx.x * 256 + threadIdx.x;
    if (e >= N_EDGES) return;
    const int d = ei[N_EDGES + e];
    const int pos = atomicAdd(&fill[d], 1);
    esrc[lscan[d] + bsumx[d >> 8] + pos] = ei[e];
}

// ---------------------------------------------------------------------------
// aggregate: one wave per dst node, lane = channel.
// pass1: lane-parallel exp(lrelu(logit)) -> STORED to ew[edge] (float4) so
//        pass2 never recomputes exp / re-gathers asrc. Butterfly -> denom.
// pass2: 4x-unrolled sequential walk; per step 8 independent xwp gathers in
//        flight (MLP vs the ~200-900cyc gather latency). Per edge VALU:
//        4 mul + 4 fma + 4 unpack (vs ~40 before).
// Self-loop analytic; head-mean (0.25) folded into inv-denoms.
// ---------------------------------------------------------------------------
__global__ __launch_bounds__(256) void aggregate(
    const int* __restrict__ esrc, const int* __restrict__ lscan,
    const int* __restrict__ bsumx, const int* __restrict__ cnt,
    const float* __restrict__ asrc, const float* __restrict__ adst,
    const unsigned* __restrict__ xwp, const float* __restrict__ xres,
    const float* __restrict__ bias, float4* __restrict__ ew,
    float* __restrict__ out)
{
    const int lane = threadIdx.x & 63;
    const int d = blockIdx.x * 4 + (threadIdx.x >> 6);
    if (d >= N_NODES) return;
    const int row = lscan[d] + bsumx[d >> 8];
    const int deg = cnt[d];
    const float4 ad = *reinterpret_cast<const float4*>(adst + (size_t)d * 4);

    // pass 1: exp + store + denom
    float dn0 = 0.f, dn1 = 0.f, dn2 = 0.f, dn3 = 0.f;
    for (int e = lane; e < deg; e += 64) {
        const int s = esrc[row + e];
        const float4 as = *reinterpret_cast<const float4*>(asrc + (size_t)s * 4);
        const float e0 = __expf(lrelu(as.x + ad.x));
        const float e1 = __expf(lrelu(as.y + ad.y));
        const float e2 = __expf(lrelu(as.z + ad.z));
        const float e3 = __expf(lrelu(as.w + ad.w));
        ew[row + e] = make_float4(e0, e1, e2, e3);   // same-pointer dep keeps order
        dn0 += e0; dn1 += e1; dn2 += e2; dn3 += e3;
    }
    #pragma unroll
    for (int off = 32; off >= 1; off >>= 1) {
        dn0 += __shfl_xor(dn0, off);
        dn1 += __shfl_xor(dn1, off);
        dn2 += __shfl_xor(dn2, off);
        dn3 += __shfl_xor(dn3, off);
    }
    const float4 asd = *reinterpret_cast<const float4*>(asrc + (size_t)d * 4);
    const float s0 = __expf(lrelu(asd.x + ad.x));
    const float s1 = __expf(lrelu(asd.y + ad.y));
    const float s2 = __expf(lrelu(asd.z + ad.z));
    const float s3 = __expf(lrelu(asd.w + ad.w));
    const float i0 = 0.25f / (dn0 + s0);
    const float i1 = 0.25f / (dn1 + s1);
    const float i2 = 0.25f / (dn2 + s2);
    const float i3 = 0.25f / (dn3 + s3);

    // pass 2: self-loop then 4x-unrolled edge walk
    const unsigned u0 = xwp[(size_t)d * 128 + lane];
    const unsigned u1 = xwp[(size_t)d * 128 + 64 + lane];
    float acc = s0 * i0 * bflo(u0) + s1 * i1 * bfhi(u0)
              + s2 * i2 * bflo(u1) + s3 * i3 * bfhi(u1);

    int e = 0;
    for (; e + 4 <= deg; e += 4) {
        const int sA = esrc[row + e];
        const int sB = esrc[row + e + 1];
        const int sC = esrc[row + e + 2];
        const int sD = esrc[row + e + 3];
        const float4 wA = ew[row + e];
        const float4 wB = ew[row + e + 1];
        const float4 wC = ew[row + e + 2];
        const float4 wD = ew[row + e + 3];
        const unsigned a0 = xwp[(size_t)sA * 128 + lane];
        const unsigned a1 = xwp[(size_t)sA * 128 + 64 + lane];
        const unsigned b0 = xwp[(size_t)sB * 128 + lane];
        const unsigned b1 = xwp[(size_t)sB * 128 + 64 + lane];
        const unsigned c0 = xwp[(size_t)sC * 128 + lane];
        const unsigned c1 = xwp[(size_t)sC * 128 + 64 + lane];
        const unsigned d0 = xwp[(size_t)sD * 128 + lane];
        const unsigned d1 = xwp[(size_t)sD * 128 + 64 + lane];
        acc += (wA.x * i0) * bflo(a0) + (wA.y * i1) * bfhi(a0)
             + (wA.z * i2) * bflo(a1) + (wA.w * i3) * bfhi(a1);
        acc += (wB.x * i0) * bflo(b0) + (wB.y * i1) * bfhi(b0)
             + (wB.z * i2) * bflo(b1) + (wB.w * i3) * bfhi(b1);
        acc += (wC.x * i0) * bflo(c0) + (wC.y * i1) * bfhi(c0)
             + (wC.z * i2) * bflo(c1) + (wC.w * i3) * bfhi(c1);
        acc += (wD.x * i0) * bflo(d0) + (wD.y * i1) * bfhi(d0)
             + (wD.z * i2) * bflo(d1) + (wD.w * i3) * bfhi(d1);
    }
    for (; e < deg; ++e) {
        const int s = esrc[row + e];
        const float4 w = ew[row + e];
        const unsigned v0 = xwp[(size_t)s * 128 + lane];
        const unsigned v1 = xwp[(size_t)s * 128 + 64 + lane];
        acc += (w.x * i0) * bflo(v0) + (w.y * i1) * bfhi(v0)
             + (w.z * i2) * bflo(v1) + (w.w * i3) * bfhi(v1);
    }
    const float v = acc + bias[lane] + xres[(size_t)d * OUT_CH + lane];
    out[(size_t)d * OUT_CH + lane] = fmaxf(v, 0.f);
}

extern "C" void kernel_launch(void* const* d_in, const int* in_sizes, int n_in,
                              void* d_out, int out_size, void* d_ws, size_t ws_size,
                              hipStream_t stream) {
    const float* x    = (const float*)d_in[0];
    const int*   ei   = (const int*)d_in[1];
    const float* W    = (const float*)d_in[2];
    const float* attS = (const float*)d_in[3];
    const float* attD = (const float*)d_in[4];
    const float* bias = (const float*)d_in[5];
    const float* Wres = (const float*)d_in[6];
    float* out = (float*)d_out;

    char* p = (char*)d_ws;
    uint4*    Bp    = (uint4*)p;      p += (size_t)NKK * NTILES * 64 * 16;   // 160 KB
    unsigned* xwp   = (unsigned*)p;   p += (size_t)N_NODES * 128 * 4;        // 25.6 MB
    float*    xres  = (float*)p;      p += (size_t)N_NODES * OUT_CH * 4;     // 12.8 MB
    float4*   ew    = (float4*)p;     p += (size_t)N_EDGES * 16;             // 12.8 MB
    float*    asrc  = (float*)p;      p += (size_t)N_NODES * HEADS * 4;
    float*    adst  = (float*)p;      p += (size_t)N_NODES * HEADS * 4;
    int*      cnt   = (int*)p;        p += (size_t)N_NODES * 4;
    int*      fill  = (int*)p;        p += (size_t)N_NODES * 4;
    int*      lscan = (int*)p;        p += (size_t)N_NODES * 4;
    int*      bsum  = (int*)p;        p += 256 * 4;
    int*      bsumx = (int*)p;        p += 256 * 4;
    int*      esrc  = (int*)p;        p += (size_t)N_EDGES * 4;

    const int nblk_scan = (N_NODES + 255) / 256;   // 196

    hipMemsetAsync(cnt, 0, (size_t)N_NODES * 2 * sizeof(int), stream);

    pack_B<<<(NKK * NTILES * 64 + 255) / 256, 256, 0, stream>>>(W, Wres, Bp);
    histogram<<<(N_EDGES + 255) / 256, 256, 0, stream>>>(ei, cnt);
    scan_local<<<nblk_scan, 256, 0, stream>>>(cnt, lscan, bsum);
    scan_bsum<<<1, 256, 0, stream>>>(bsum, bsumx, nblk_scan);
    scatter<<<(N_EDGES + 255) / 256, 256, 0, stream>>>(ei, lscan, bsumx, fill, esrc);
    gemm_node<<<(N_NODES + 63) / 64, 256, 0, stream>>>(
        x, Bp, attS, attD, xwp, xres, asrc, adst);
    aggregate<<<(N_NODES + 3) / 4, 256, 0, stream>>>(
        esrc, lscan, bsumx, cnt, asrc, adst, xwp, xres, bias, ew, out);
}